// Round 15
// baseline (138.038 us; speedup 1.0000x reference)
//
#include <hip/hip_runtime.h>
#include <hip/hip_bf16.h>

#define N_POS 9216
#define NCHUNK 9
#define BATCH 8
#define CDIM 64
#define HEADS 4
#define EPS 1e-5f

// ws layout: stats fp32(128) | Psum fp32(32*9*1024) | Wbf16 | ybf bf16
#define PSUM_SZ ((size_t)32 * NCHUNK * 1024)    // 294912 floats
#define WBF_BYTES ((size_t)384 * 64 * 2)

typedef __attribute__((ext_vector_type(8))) short short8;
typedef __attribute__((ext_vector_type(4))) float f32x4;

static __device__ inline unsigned pk2(float a, float b) {
    __hip_bfloat162 h2(__float2bfloat16(a), __float2bfloat16(b));
    return *reinterpret_cast<unsigned*>(&h2);
}
static __device__ inline float bf2f(short s) {
    union { unsigned u; float f; } c; c.u = ((unsigned)(unsigned short)s) << 16; return c.f;
}

// Wqkv fp32 -> bf16; zeroes stats + Psum (73760 float4 total).
__global__ __launch_bounds__(256) void wprep_kernel(const float* __restrict__ Wqkv,
        __hip_bfloat16* __restrict__ wbf, float* __restrict__ zbase) {
    int i = blockIdx.x * 256 + threadIdx.x;
    if (i < 6144) {
        float4 v = ((const float4*)Wqkv)[i];
        uint2 u; u.x = pk2(v.x, v.y); u.y = pk2(v.z, v.w);
        ((uint2*)wbf)[i] = u;
    }
    if (i < (128 + (int)PSUM_SZ) / 4)
        ((float4*)zbase)[i] = (float4){0.f, 0.f, 0.f, 0.f};
}

// q,k + P via global atomicAdd. Grid (72, 8): 128 positions per block as TWO
// serial 64-pos sub-tiles sharing LDS; P accumulates in registers across both.
__global__ __launch_bounds__(256) void qkp_kernel(const float* __restrict__ x,
        const __hip_bfloat16* __restrict__ wbf, float* __restrict__ Psum) {
    int bx = blockIdx.x;            // 72 = 9 ck x 8 pt
    int b  = blockIdx.y;
    int ck = bx >> 3;
    __shared__ __align__(16) char lraw[36864];
    __hip_bfloat16 (*xs)[72]  = (__hip_bfloat16(*)[72])lraw;   // [64][72]
    __hip_bfloat16 (*skT)[72] = (__hip_bfloat16(*)[72])lraw;   // [256][72] (aliases xs)
    int t = threadIdx.x, w = t >> 6, l = t & 63;
    int l15 = l & 15, quad = l >> 4;

    f32x4 pac[2][2];
    pac[0][0] = (f32x4){0,0,0,0}; pac[0][1] = (f32x4){0,0,0,0};
    pac[1][0] = (f32x4){0,0,0,0}; pac[1][1] = (f32x4){0,0,0,0};

    for (int half = 0; half < 2; ++half) {
        int n0 = bx * 128 + half * 64;
        {
            int p = t & 63, cbase = (t >> 6) * 16;
            const float* xb = x + (size_t)b * CDIM * N_POS + n0 + p;
            #pragma unroll
            for (int j = 0; j < 16; j += 4) {
                float v0 = xb[(size_t)(cbase + j + 0) * N_POS];
                float v1 = xb[(size_t)(cbase + j + 1) * N_POS];
                float v2 = xb[(size_t)(cbase + j + 2) * N_POS];
                float v3 = xb[(size_t)(cbase + j + 3) * N_POS];
                uint2 u; u.x = pk2(v0, v1); u.y = pk2(v2, v3);
                *reinterpret_cast<uint2*>(&xs[p][cbase + j]) = u;
            }
        }
        __syncthreads();

        f32x4 acc[4][4];
        #pragma unroll
        for (int mt = 0; mt < 4; ++mt)
            #pragma unroll
            for (int nt = 0; nt < 4; ++nt) acc[mt][nt] = (f32x4){0.f, 0.f, 0.f, 0.f};
        #pragma unroll
        for (int ks = 0; ks < 2; ++ks) {
            int k0 = ks * 32 + quad * 8;
            short8 av[4];
            #pragma unroll
            for (int mt = 0; mt < 4; ++mt)
                av[mt] = *reinterpret_cast<const short8*>(&xs[mt * 16 + l15][k0]);
            #pragma unroll
            for (int nt = 0; nt < 4; ++nt) {
                short8 bw = *reinterpret_cast<const short8*>(wbf + (size_t)(w * 64 + nt * 16 + l15) * 64 + k0);
                #pragma unroll
                for (int mt = 0; mt < 4; ++mt)
                    acc[mt][nt] = __builtin_amdgcn_mfma_f32_16x16x32_bf16(av[mt], bw, acc[mt][nt], 0, 0, 0);
            }
        }
        __syncthreads();   // xs dead; lraw becomes skT

        #pragma unroll
        for (int nt = 0; nt < 4; ++nt) {
            int ch = w * 64 + nt * 16 + l15;
            #pragma unroll
            for (int mt = 0; mt < 4; ++mt) {
                uint2 u;
                u.x = pk2(acc[mt][nt][0], acc[mt][nt][1]);
                u.y = pk2(acc[mt][nt][2], acc[mt][nt][3]);
                *reinterpret_cast<uint2*>(&skT[ch][mt * 16 + quad * 4]) = u;
            }
        }
        __syncthreads();

        {
            int p = t & 63, h = t >> 6;
            float kr[32]; float mx = -1e30f;
            #pragma unroll
            for (int d = 0; d < 32; ++d) { kr[d] = bf2f(*(const short*)&skT[128 + h * 32 + d][p]); mx = fmaxf(mx, kr[d]); }
            float s = 0.f;
            #pragma unroll
            for (int d = 0; d < 32; ++d) { kr[d] = __expf(kr[d] - mx); s += kr[d]; }
            float is = 1.f / s;
            #pragma unroll
            for (int d = 0; d < 32; ++d) skT[128 + h * 32 + d][p] = __float2bfloat16(kr[d] * is);
            #pragma unroll
            for (int d = 0; d < 32; ++d) {
                float qv = bf2f(*(const short*)&skT[h * 32 + d][p]);
                skT[h * 32 + d][p] = __float2bfloat16(__expf(qv));
            }
        }
        __syncthreads();

        #pragma unroll
        for (int step = 0; step < 2; ++step) {
            int k0 = step * 32 + quad * 8;
            short8 bk[2];
            #pragma unroll
            for (int nt = 0; nt < 2; ++nt)
                bk[nt] = *reinterpret_cast<const short8*>(&skT[128 + w * 32 + nt * 16 + l15][k0]);
            #pragma unroll
            for (int mt = 0; mt < 2; ++mt) {
                short8 aq = *reinterpret_cast<const short8*>(&skT[w * 32 + mt * 16 + l15][k0]);
                pac[mt][0] = __builtin_amdgcn_mfma_f32_16x16x32_bf16(aq, bk[0], pac[mt][0], 0, 0, 0);
                pac[mt][1] = __builtin_amdgcn_mfma_f32_16x16x32_bf16(aq, bk[1], pac[mt][1], 0, 0, 0);
            }
        }
        __syncthreads();   // protect skT before next half's restage
    }

    float* Pp = Psum + ((size_t)(b * 4 + w) * NCHUNK + ck) * 1024;
    #pragma unroll
    for (int mt = 0; mt < 2; ++mt)
        #pragma unroll
        for (int nt = 0; nt < 2; ++nt)
            #pragma unroll
            for (int r = 0; r < 4; ++r)
                atomicAdd(&Pp[(mt * 16 + quad * 4 + r) * 32 + nt * 16 + l15], pac[mt][nt][r]);
}

// Fused U' + v + y: per-block U' recompute (8x redundant, tiny), v = Wv.x
// (MFMA->LDS), y = U'.v^T (MFMA, A from LDS Ubuf), bias + GN stats; y as bf16.
__global__ __launch_bounds__(256) void vy_kernel(const float* __restrict__ x,
        const __hip_bfloat16* __restrict__ wbf, const float* __restrict__ Psum,
        const float* __restrict__ Wout, const float* __restrict__ bout,
        __hip_bfloat16* __restrict__ ybf, float* __restrict__ stats) {
    int bx = blockIdx.x;   // 72 tiles of 128 positions
    int b  = blockIdx.y;   // 8
    int ck = bx >> 3;
    int n0 = bx * 128;
    __shared__ __align__(16) char lraw[34816];
    __hip_bfloat16 (*xs)[72]    = (__hip_bfloat16(*)[72])lraw;    // [128][72]
    __hip_bfloat16 (*vbuf)[136] = (__hip_bfloat16(*)[136])lraw;   // [128][136] (aliases xs)
    float (*Pl4)[32][32] = (float(*)[32][32])lraw;                // [4][32][32] (prologue scratch)
    __shared__ __align__(16) __hip_bfloat16 Ubuf[64][136];        // 136-stride: 2-way banks
    __shared__ float iZ4[4][32];
    __shared__ float gsum[8], gsq[8];
    int t = threadIdx.x, w = t >> 6, l = t & 63;
    int l15 = l & 15, quad = l >> 4;
    if (t < 8) { gsum[t] = 0.f; gsq[t] = 0.f; }

    // ---- Prologue: U'[o][c] for this (b, ck) from Psum ----
    {
        const float4* Pb = (const float4*)(Psum + ((size_t)b * 4 * NCHUNK + ck) * 1024);
        #pragma unroll
        for (int h = 0; h < 4; ++h)
            ((float4*)Pl4[h])[t] = Pb[(size_t)h * NCHUNK * 256 + t];
    }
    __syncthreads();
    if (t < 128) {
        int h = t >> 5, d = t & 31;
        float s = 0.f;
        #pragma unroll
        for (int c = 0; c < 32; ++c) s += Pl4[h][d][c];
        iZ4[h][d] = 1.f / s;
    }
    __syncthreads();
    {
        int o = t & 63, wv = t >> 6;
        #pragma unroll
        for (int h = 0; h < 4; ++h) {
            float wz[32];
            const float4* wr = (const float4*)(Wout + (size_t)o * 128 + h * 32);
            #pragma unroll
            for (int j = 0; j < 8; ++j) {
                float4 f = wr[j];
                wz[j*4+0] = f.x * iZ4[h][j*4+0]; wz[j*4+1] = f.y * iZ4[h][j*4+1];
                wz[j*4+2] = f.z * iZ4[h][j*4+2]; wz[j*4+3] = f.w * iZ4[h][j*4+3];
            }
            float ua[8];
            #pragma unroll
            for (int j = 0; j < 8; ++j) ua[j] = 0.f;
            for (int d = 0; d < 32; ++d) {
                float wd = wz[d];
                #pragma unroll
                for (int j = 0; j < 8; ++j) ua[j] += wd * Pl4[h][d][wv * 8 + j];
            }
            uint4 up;
            up.x = pk2(ua[0], ua[1]); up.y = pk2(ua[2], ua[3]);
            up.z = pk2(ua[4], ua[5]); up.w = pk2(ua[6], ua[7]);
            *reinterpret_cast<uint4*>(&Ubuf[o][h * 32 + wv * 8]) = up;
        }
    }
    __syncthreads();   // Pl4 reads done; lraw free for x staging

    // ---- stage x tile ----
    {
        int p = t & 127, cbase = (t >> 7) * 32;
        const float* xb = x + (size_t)b * CDIM * N_POS + n0 + p;
        #pragma unroll
        for (int j = 0; j < 32; j += 4) {
            float v0 = xb[(size_t)(cbase + j + 0) * N_POS];
            float v1 = xb[(size_t)(cbase + j + 1) * N_POS];
            float v2 = xb[(size_t)(cbase + j + 2) * N_POS];
            float v3 = xb[(size_t)(cbase + j + 3) * N_POS];
            uint2 u; u.x = pk2(v0, v1); u.y = pk2(v2, v3);
            *reinterpret_cast<uint2*>(&xs[p][cbase + j]) = u;
        }
    }
    __syncthreads();

    // ---- v MFMA: D[m=ch][n=p]; wave w owns p range [w*32, w*32+32) ----
    int nw = w * 32;
    {
        f32x4 vacc[8][2];
        #pragma unroll
        for (int mt = 0; mt < 8; ++mt) { vacc[mt][0] = (f32x4){0,0,0,0}; vacc[mt][1] = (f32x4){0,0,0,0}; }
        #pragma unroll
        for (int ks = 0; ks < 2; ++ks) {
            int k0 = ks * 32 + quad * 8;
            short8 bfr[2];
            #pragma unroll
            for (int nt = 0; nt < 2; ++nt)
                bfr[nt] = *reinterpret_cast<const short8*>(&xs[nw + nt * 16 + l15][k0]);
            #pragma unroll
            for (int mt = 0; mt < 8; ++mt) {
                short8 afr = *reinterpret_cast<const short8*>(wbf + (size_t)(256 + mt * 16 + l15) * 64 + k0);
                vacc[mt][0] = __builtin_amdgcn_mfma_f32_16x16x32_bf16(afr, bfr[0], vacc[mt][0], 0, 0, 0);
                vacc[mt][1] = __builtin_amdgcn_mfma_f32_16x16x32_bf16(afr, bfr[1], vacc[mt][1], 0, 0, 0);
            }
        }
        __syncthreads();   // xs dead; lraw becomes vbuf

        #pragma unroll
        for (int mt = 0; mt < 8; ++mt)
            #pragma unroll
            for (int nt = 0; nt < 2; ++nt) {
                int p = nw + nt * 16 + l15;
                uint2 u;
                u.x = pk2(vacc[mt][nt][0], vacc[mt][nt][1]);
                u.y = pk2(vacc[mt][nt][2], vacc[mt][nt][3]);
                *reinterpret_cast<uint2*>(&vbuf[p][mt * 16 + quad * 4]) = u;
            }
    }
    __syncthreads();

    // ---- y MFMA: A = U' rows (LDS Ubuf), B = v position rows (LDS vbuf) ----
    f32x4 acc[4][2];
    #pragma unroll
    for (int mt = 0; mt < 4; ++mt) { acc[mt][0] = (f32x4){0,0,0,0}; acc[mt][1] = (f32x4){0,0,0,0}; }
    #pragma unroll
    for (int ks = 0; ks < 4; ++ks) {
        int k0 = ks * 32 + quad * 8;
        short8 bf[2];
        #pragma unroll
        for (int nt = 0; nt < 2; ++nt)
            bf[nt] = *reinterpret_cast<const short8*>(&vbuf[nw + nt * 16 + l15][k0]);
        #pragma unroll
        for (int mt = 0; mt < 4; ++mt) {
            short8 af = *reinterpret_cast<const short8*>(&Ubuf[mt * 16 + l15][k0]);
            acc[mt][0] = __builtin_amdgcn_mfma_f32_16x16x32_bf16(af, bf[0], acc[mt][0], 0, 0, 0);
            acc[mt][1] = __builtin_amdgcn_mfma_f32_16x16x32_bf16(af, bf[1], acc[mt][1], 0, 0, 0);
        }
    }
    float gsl[4], gql[4];
    #pragma unroll
    for (int mt = 0; mt < 4; ++mt) { gsl[mt] = 0.f; gql[mt] = 0.f; }
    __hip_bfloat16* yb = ybf + (size_t)b * CDIM * N_POS;
    int nbase = n0 + nw;
    #pragma unroll
    for (int mt = 0; mt < 4; ++mt) {
        float4 bo = *reinterpret_cast<const float4*>(bout + mt * 16 + quad * 4);
        const float* bop = reinterpret_cast<const float*>(&bo);
        #pragma unroll
        for (int nt = 0; nt < 2; ++nt) {
            int n = nbase + nt * 16 + l15;
            #pragma unroll
            for (int r = 0; r < 4; ++r) {
                int o = mt * 16 + quad * 4 + r;
                float val = acc[mt][nt][r] + bop[r];
                yb[(size_t)o * N_POS + n] = __float2bfloat16(val);
                gsl[mt] += val; gql[mt] += val * val;
            }
        }
    }
    #pragma unroll
    for (int off = 16; off >= 1; off >>= 1) {
        #pragma unroll
        for (int mt = 0; mt < 4; ++mt) {
            gsl[mt] += __shfl_xor(gsl[mt], off, 64);
            gql[mt] += __shfl_xor(gql[mt], off, 64);
        }
    }
    if (l == 0 || l == 32) {
        int qh = quad >> 1;
        #pragma unroll
        for (int mt = 0; mt < 4; ++mt) {
            atomicAdd(&gsum[2 * mt + qh], gsl[mt]);
            atomicAdd(&gsq[2 * mt + qh], gql[mt]);
        }
    }
    __syncthreads();
    if (t < 8) {
        atomicAdd(&stats[(b * 8 + t) * 2],     gsum[t]);
        atomicAdd(&stats[(b * 8 + t) * 2 + 1], gsq[t]);
    }
}

// GN normalize: read bf16 pre-norm y, write fp32 out. Grid (9, 512): by = b*64+c.
__global__ __launch_bounds__(256) void gn_kernel(const __hip_bfloat16* __restrict__ ybf,
        float* __restrict__ out, const float* __restrict__ stats,
        const float* __restrict__ gamma, const float* __restrict__ beta) {
    int bc = blockIdx.y;            // 512 = b*64 + c
    int c = bc & 63, b = bc >> 6;
    int g = c >> 3;
    float s = stats[(b * 8 + g) * 2], q = stats[(b * 8 + g) * 2 + 1];
    const float invN = 1.f / (8.f * N_POS);
    float mean = s * invN;
    float var = q * invN - mean * mean;
    float sc = rsqrtf(var + EPS);
    float ga = gamma[c] * sc;
    float be = beta[c] - mean * sc * gamma[c];
    size_t base = ((size_t)b * CDIM + c) * N_POS + (size_t)(blockIdx.x * 256 + threadIdx.x) * 4;
    uint2 u = *reinterpret_cast<const uint2*>(ybf + base);
    float4 v;
    v.x = bf2f((short)(u.x & 0xffff)); v.y = bf2f((short)(u.x >> 16));
    v.z = bf2f((short)(u.y & 0xffff)); v.w = bf2f((short)(u.y >> 16));
    v.x = v.x * ga + be; v.y = v.y * ga + be; v.z = v.z * ga + be; v.w = v.w * ga + be;
    *reinterpret_cast<float4*>(out + base) = v;
}

extern "C" void kernel_launch(void* const* d_in, const int* in_sizes, int n_in,
                              void* d_out, int out_size, void* d_ws, size_t ws_size,
                              hipStream_t stream) {
    const float* x     = (const float*)d_in[0];
    const float* Wqkv  = (const float*)d_in[1];
    const float* Wout  = (const float*)d_in[2];
    const float* bout  = (const float*)d_in[3];
    const float* gamma = (const float*)d_in[4];
    const float* beta  = (const float*)d_in[5];
    float* out = (float*)d_out;

    float* stats = (float*)d_ws;
    float* Psum  = stats + 128;
    __hip_bfloat16* wbf = (__hip_bfloat16*)(Psum + PSUM_SZ);
    __hip_bfloat16* ybf = (__hip_bfloat16*)((char*)wbf + WBF_BYTES);

    wprep_kernel<<<dim3(289), 256, 0, stream>>>(Wqkv, wbf, stats);
    qkp_kernel<<<dim3(72, BATCH), 256, 0, stream>>>(x, wbf, Psum);
    vy_kernel<<<dim3(72, BATCH), 256, 0, stream>>>(x, wbf, Psum, Wout, bout, ybf, stats);
    gn_kernel<<<dim3(9, 512), 256, 0, stream>>>(ybf, out, stats, gamma, beta);
}

// Round 16
// 123.322 us; speedup vs baseline: 1.1193x; 1.1193x over previous
//
#include <hip/hip_runtime.h>
#include <hip/hip_bf16.h>

#define N_POS 9216
#define NCHUNK 9
#define BATCH 8
#define CDIM 64
#define HEADS 4
#define EPS 1e-5f

// ws layout: stats fp32(128) | Pparts fp32 8x(32*9*1024) | U' bf16 | Wbf16 | ybf bf16
#define PPART_SZ ((size_t)32 * NCHUNK * 1024)   // floats per partial
#define NPART 8
#define UBF_BYTES ((size_t)BATCH * NCHUNK * 64 * 128 * 2)
#define WBF_BYTES ((size_t)384 * 64 * 2)

typedef __attribute__((ext_vector_type(8))) short short8;
typedef __attribute__((ext_vector_type(4))) float f32x4;

static __device__ inline unsigned pk2(float a, float b) {
    __hip_bfloat162 h2(__float2bfloat16(a), __float2bfloat16(b));
    return *reinterpret_cast<unsigned*>(&h2);
}
static __device__ inline float bf2f(short s) {
    union { unsigned u; float f; } c; c.u = ((unsigned)(unsigned short)s) << 16; return c.f;
}

// Wqkv fp32 [384][64] -> bf16 [384][64]; also zeroes GN stats.
__global__ __launch_bounds__(256) void wprep_kernel(const float* __restrict__ Wqkv,
        __hip_bfloat16* __restrict__ wbf, float* __restrict__ stats) {
    int i = blockIdx.x * 256 + threadIdx.x;   // over 6144 float4
    if (i < 6144) {
        float4 v = ((const float4*)Wqkv)[i];
        uint2 u; u.x = pk2(v.x, v.y); u.y = pk2(v.z, v.w);
        ((uint2*)wbf)[i] = u;
    }
    if (i < 128) stats[i] = 0.f;
}

// q,k + P-partial. Grid (72, 8): 128 positions per block as TWO serial 64-pos
// sub-tiles sharing LDS; P accumulates in registers across both.
// Per sub-tile: D[p][ch]=x.Wqk MFMA -> b64 transpose to channel-major skT
// (q channels get exp() fused into the transpose) -> k channel-softmax ->
// per-head P(32x32) MFMA (K=64). q-normalization deferred (rowsum identity).
__global__ __launch_bounds__(256) void qkp_kernel(const float* __restrict__ x,
        const __hip_bfloat16* __restrict__ wbf, float* __restrict__ Pparts) {
    int bx = blockIdx.x;            // 72 = 9 ck x 8 pt
    int b  = blockIdx.y;
    int ck = bx >> 3, pt = bx & 7;
    __shared__ __align__(16) char lraw[36864];
    __hip_bfloat16 (*xs)[72]  = (__hip_bfloat16(*)[72])lraw;   // [64][72]
    __hip_bfloat16 (*skT)[72] = (__hip_bfloat16(*)[72])lraw;   // [256][72] (aliases xs)
    int t = threadIdx.x, w = t >> 6, l = t & 63;
    int l15 = l & 15, quad = l >> 4;

    f32x4 pac[2][2];
    pac[0][0] = (f32x4){0,0,0,0}; pac[0][1] = (f32x4){0,0,0,0};
    pac[1][0] = (f32x4){0,0,0,0}; pac[1][1] = (f32x4){0,0,0,0};

    for (int half = 0; half < 2; ++half) {
        int n0 = bx * 128 + half * 64;
        {
            int p = t & 63, cbase = (t >> 6) * 16;
            const float* xb = x + (size_t)b * CDIM * N_POS + n0 + p;
            #pragma unroll
            for (int j = 0; j < 16; j += 4) {
                float v0 = xb[(size_t)(cbase + j + 0) * N_POS];
                float v1 = xb[(size_t)(cbase + j + 1) * N_POS];
                float v2 = xb[(size_t)(cbase + j + 2) * N_POS];
                float v3 = xb[(size_t)(cbase + j + 3) * N_POS];
                uint2 u; u.x = pk2(v0, v1); u.y = pk2(v2, v3);
                *reinterpret_cast<uint2*>(&xs[p][cbase + j]) = u;
            }
        }
        __syncthreads();

        f32x4 acc[4][4];
        #pragma unroll
        for (int mt = 0; mt < 4; ++mt)
            #pragma unroll
            for (int nt = 0; nt < 4; ++nt) acc[mt][nt] = (f32x4){0.f, 0.f, 0.f, 0.f};
        #pragma unroll
        for (int ks = 0; ks < 2; ++ks) {
            int k0 = ks * 32 + quad * 8;
            short8 av[4];
            #pragma unroll
            for (int mt = 0; mt < 4; ++mt)
                av[mt] = *reinterpret_cast<const short8*>(&xs[mt * 16 + l15][k0]);
            #pragma unroll
            for (int nt = 0; nt < 4; ++nt) {
                short8 bw = *reinterpret_cast<const short8*>(wbf + (size_t)(w * 64 + nt * 16 + l15) * 64 + k0);
                #pragma unroll
                for (int mt = 0; mt < 4; ++mt)
                    acc[mt][nt] = __builtin_amdgcn_mfma_f32_16x16x32_bf16(av[mt], bw, acc[mt][nt], 0, 0, 0);
            }
        }
        __syncthreads();   // xs dead; lraw becomes skT

        // transpose: skT[ch][p]; q channels (waves 0,1) get exp() fused here
        if (w < 2) {
            #pragma unroll
            for (int nt = 0; nt < 4; ++nt) {
                int ch = w * 64 + nt * 16 + l15;
                #pragma unroll
                for (int mt = 0; mt < 4; ++mt) {
                    uint2 u;
                    u.x = pk2(__expf(acc[mt][nt][0]), __expf(acc[mt][nt][1]));
                    u.y = pk2(__expf(acc[mt][nt][2]), __expf(acc[mt][nt][3]));
                    *reinterpret_cast<uint2*>(&skT[ch][mt * 16 + quad * 4]) = u;
                }
            }
        } else {
            #pragma unroll
            for (int nt = 0; nt < 4; ++nt) {
                int ch = w * 64 + nt * 16 + l15;
                #pragma unroll
                for (int mt = 0; mt < 4; ++mt) {
                    uint2 u;
                    u.x = pk2(acc[mt][nt][0], acc[mt][nt][1]);
                    u.y = pk2(acc[mt][nt][2], acc[mt][nt][3]);
                    *reinterpret_cast<uint2*>(&skT[ch][mt * 16 + quad * 4]) = u;
                }
            }
        }
        __syncthreads();

        // k channel-softmax only (q already exponentiated in transpose)
        {
            int p = t & 63, h = t >> 6;
            float kr[32]; float mx = -1e30f;
            #pragma unroll
            for (int d = 0; d < 32; ++d) { kr[d] = bf2f(*(const short*)&skT[128 + h * 32 + d][p]); mx = fmaxf(mx, kr[d]); }
            float s = 0.f;
            #pragma unroll
            for (int d = 0; d < 32; ++d) { kr[d] = __expf(kr[d] - mx); s += kr[d]; }
            float is = 1.f / s;
            #pragma unroll
            for (int d = 0; d < 32; ++d) skT[128 + h * 32 + d][p] = __float2bfloat16(kr[d] * is);
        }
        __syncthreads();

        #pragma unroll
        for (int step = 0; step < 2; ++step) {
            int k0 = step * 32 + quad * 8;
            short8 bk[2];
            #pragma unroll
            for (int nt = 0; nt < 2; ++nt)
                bk[nt] = *reinterpret_cast<const short8*>(&skT[128 + w * 32 + nt * 16 + l15][k0]);
            #pragma unroll
            for (int mt = 0; mt < 2; ++mt) {
                short8 aq = *reinterpret_cast<const short8*>(&skT[w * 32 + mt * 16 + l15][k0]);
                pac[mt][0] = __builtin_amdgcn_mfma_f32_16x16x32_bf16(aq, bk[0], pac[mt][0], 0, 0, 0);
                pac[mt][1] = __builtin_amdgcn_mfma_f32_16x16x32_bf16(aq, bk[1], pac[mt][1], 0, 0, 0);
            }
        }
        __syncthreads();   // protect skT before next half's restage
    }

    float* Pp = Pparts + (size_t)pt * PPART_SZ + ((size_t)(b * 4 + w) * NCHUNK + ck) * 1024;
    #pragma unroll
    for (int mt = 0; mt < 2; ++mt)
        #pragma unroll
        for (int nt = 0; nt < 2; ++nt)
            #pragma unroll
            for (int r = 0; r < 4; ++r)
                Pp[(mt * 16 + quad * 4 + r) * 32 + nt * 16 + l15] = pac[mt][nt][r];
}

// U'[o][h*32+dd] = sum_d Wout[o][h*32+d] * (1/Z_d) * P[d][dd];  Z_d = rowsum(P).
// Sums the 8 partials.
__global__ __launch_bounds__(256) void umat_kernel(const float* __restrict__ Wout,
        const float* __restrict__ Pparts, __hip_bfloat16* __restrict__ Ubf) {
    int ck = blockIdx.x, b = blockIdx.y, h = blockIdx.z;
    int bh = b * 4 + h;
    int t = threadIdx.x;
    __shared__ float Pl[32][32];
    __shared__ float iZ[32];
    size_t base4 = ((size_t)bh * NCHUNK + ck) * 256;
    {
        const float4* P0 = (const float4*)Pparts + base4 + t;
        float4 s = (float4){0.f, 0.f, 0.f, 0.f};
        #pragma unroll
        for (int j = 0; j < NPART; ++j) {
            float4 a = P0[j * (PPART_SZ / 4)];
            s.x += a.x; s.y += a.y; s.z += a.z; s.w += a.w;
        }
        ((float4*)Pl)[t] = s;
    }
    __syncthreads();
    if (t < 32) {
        float s = 0.f;
        #pragma unroll
        for (int c = 0; c < 32; ++c) s += Pl[t][c];
        iZ[t] = 1.f / s;
    }
    __syncthreads();
    int o = t & 63, wv = t >> 6;
    float wz[32];
    {
        const float4* wr = (const float4*)(Wout + (size_t)o * 128 + h * 32);
        #pragma unroll
        for (int j = 0; j < 8; ++j) {
            float4 f = wr[j];
            wz[j*4+0] = f.x * iZ[j*4+0]; wz[j*4+1] = f.y * iZ[j*4+1];
            wz[j*4+2] = f.z * iZ[j*4+2]; wz[j*4+3] = f.w * iZ[j*4+3];
        }
    }
    float ua[8];
    #pragma unroll
    for (int j = 0; j < 8; ++j) ua[j] = 0.f;
    for (int d = 0; d < 32; ++d) {
        float wd = wz[d];
        #pragma unroll
        for (int j = 0; j < 8; ++j) ua[j] += wd * Pl[d][wv * 8 + j];
    }
    uint4 up;
    up.x = pk2(ua[0], ua[1]); up.y = pk2(ua[2], ua[3]);
    up.z = pk2(ua[4], ua[5]); up.w = pk2(ua[6], ua[7]);
    __hip_bfloat16* Up = Ubf + ((size_t)(b * NCHUNK + ck) * 64 + o) * 128 + h * 32 + wv * 8;
    *reinterpret_cast<uint4*>(Up) = up;
}

// Fused v + y: v = Wv.x-tile (MFMA -> LDS), then y = U'.v^T (MFMA from LDS);
// fused bias + GN stats. Writes pre-norm y as bf16 (rounding error is rescaled
// by the same rstd at normalization -> ~0.4% of unit scale).
__global__ __launch_bounds__(256) void vy_kernel(const float* __restrict__ x,
        const __hip_bfloat16* __restrict__ wbf, const __hip_bfloat16* __restrict__ Ubf,
        const float* __restrict__ bout, __hip_bfloat16* __restrict__ ybf,
        float* __restrict__ stats) {
    int bx = blockIdx.x;   // 72 tiles of 128 positions
    int b  = blockIdx.y;   // 8
    int ck = bx >> 3;
    int n0 = bx * 128;
    __shared__ __align__(16) char lraw[34816];
    __hip_bfloat16 (*xs)[72]    = (__hip_bfloat16(*)[72])lraw;    // [128][72]
    __hip_bfloat16 (*vbuf)[136] = (__hip_bfloat16(*)[136])lraw;   // [128][136] (aliases xs)
    __shared__ float gsum[8], gsq[8];
    int t = threadIdx.x, w = t >> 6, l = t & 63;
    int l15 = l & 15, quad = l >> 4;
    if (t < 8) { gsum[t] = 0.f; gsq[t] = 0.f; }

    // stage x tile: 2 threads per position, 32 channels each
    {
        int p = t & 127, cbase = (t >> 7) * 32;
        const float* xb = x + (size_t)b * CDIM * N_POS + n0 + p;
        #pragma unroll
        for (int j = 0; j < 32; j += 4) {
            float v0 = xb[(size_t)(cbase + j + 0) * N_POS];
            float v1 = xb[(size_t)(cbase + j + 1) * N_POS];
            float v2 = xb[(size_t)(cbase + j + 2) * N_POS];
            float v3 = xb[(size_t)(cbase + j + 3) * N_POS];
            uint2 u; u.x = pk2(v0, v1); u.y = pk2(v2, v3);
            *reinterpret_cast<uint2*>(&xs[p][cbase + j]) = u;
        }
    }
    __syncthreads();

    // v MFMA: D[m=ch][n=p]; wave w owns p range [w*32, w*32+32)
    int nw = w * 32;
    {
        f32x4 vacc[8][2];
        #pragma unroll
        for (int mt = 0; mt < 8; ++mt) { vacc[mt][0] = (f32x4){0,0,0,0}; vacc[mt][1] = (f32x4){0,0,0,0}; }
        #pragma unroll
        for (int ks = 0; ks < 2; ++ks) {
            int k0 = ks * 32 + quad * 8;
            short8 bfr[2];
            #pragma unroll
            for (int nt = 0; nt < 2; ++nt)
                bfr[nt] = *reinterpret_cast<const short8*>(&xs[nw + nt * 16 + l15][k0]);
            #pragma unroll
            for (int mt = 0; mt < 8; ++mt) {
                short8 afr = *reinterpret_cast<const short8*>(wbf + (size_t)(256 + mt * 16 + l15) * 64 + k0);
                vacc[mt][0] = __builtin_amdgcn_mfma_f32_16x16x32_bf16(afr, bfr[0], vacc[mt][0], 0, 0, 0);
                vacc[mt][1] = __builtin_amdgcn_mfma_f32_16x16x32_bf16(afr, bfr[1], vacc[mt][1], 0, 0, 0);
            }
        }
        __syncthreads();   // xs dead; lraw becomes vbuf

        #pragma unroll
        for (int mt = 0; mt < 8; ++mt)
            #pragma unroll
            for (int nt = 0; nt < 2; ++nt) {
                int p = nw + nt * 16 + l15;
                uint2 u;
                u.x = pk2(vacc[mt][nt][0], vacc[mt][nt][1]);
                u.y = pk2(vacc[mt][nt][2], vacc[mt][nt][3]);
                *reinterpret_cast<uint2*>(&vbuf[p][mt * 16 + quad * 4]) = u;
            }
    }
    __syncthreads();

    // y MFMA: A = U' rows (global, L2), B = v position rows (LDS)
    const __hip_bfloat16* Ub = Ubf + (size_t)(b * NCHUNK + ck) * 64 * 128;
    f32x4 acc[4][2];
    #pragma unroll
    for (int mt = 0; mt < 4; ++mt) { acc[mt][0] = (f32x4){0,0,0,0}; acc[mt][1] = (f32x4){0,0,0,0}; }
    #pragma unroll
    for (int ks = 0; ks < 4; ++ks) {
        int k0 = ks * 32 + quad * 8;
        short8 bf[2];
        #pragma unroll
        for (int nt = 0; nt < 2; ++nt)
            bf[nt] = *reinterpret_cast<const short8*>(&vbuf[nw + nt * 16 + l15][k0]);
        #pragma unroll
        for (int mt = 0; mt < 4; ++mt) {
            short8 af = *reinterpret_cast<const short8*>(Ub + (size_t)(mt * 16 + l15) * 128 + k0);
            acc[mt][0] = __builtin_amdgcn_mfma_f32_16x16x32_bf16(af, bf[0], acc[mt][0], 0, 0, 0);
            acc[mt][1] = __builtin_amdgcn_mfma_f32_16x16x32_bf16(af, bf[1], acc[mt][1], 0, 0, 0);
        }
    }
    float gsl[4], gql[4];
    #pragma unroll
    for (int mt = 0; mt < 4; ++mt) { gsl[mt] = 0.f; gql[mt] = 0.f; }
    __hip_bfloat16* yb = ybf + (size_t)b * CDIM * N_POS;
    int nbase = n0 + nw;
    #pragma unroll
    for (int mt = 0; mt < 4; ++mt) {
        float4 bo = *reinterpret_cast<const float4*>(bout + mt * 16 + quad * 4);
        const float* bop = reinterpret_cast<const float*>(&bo);
        #pragma unroll
        for (int nt = 0; nt < 2; ++nt) {
            int n = nbase + nt * 16 + l15;
            #pragma unroll
            for (int r = 0; r < 4; ++r) {
                int o = mt * 16 + quad * 4 + r;
                float val = acc[mt][nt][r] + bop[r];
                yb[(size_t)o * N_POS + n] = __float2bfloat16(val);
                gsl[mt] += val; gql[mt] += val * val;
            }
        }
    }
    #pragma unroll
    for (int off = 16; off >= 1; off >>= 1) {
        #pragma unroll
        for (int mt = 0; mt < 4; ++mt) {
            gsl[mt] += __shfl_xor(gsl[mt], off, 64);
            gql[mt] += __shfl_xor(gql[mt], off, 64);
        }
    }
    if (l == 0 || l == 32) {
        int qh = quad >> 1;
        #pragma unroll
        for (int mt = 0; mt < 4; ++mt) {
            atomicAdd(&gsum[2 * mt + qh], gsl[mt]);
            atomicAdd(&gsq[2 * mt + qh], gql[mt]);
        }
    }
    __syncthreads();
    if (t < 8) {
        atomicAdd(&stats[(b * 8 + t) * 2],     gsum[t]);
        atomicAdd(&stats[(b * 8 + t) * 2 + 1], gsq[t]);
    }
}

// GN normalize: read bf16 pre-norm y, write fp32 out. Grid (9, 512): by = b*64+c.
__global__ __launch_bounds__(256) void gn_kernel(const __hip_bfloat16* __restrict__ ybf,
        float* __restrict__ out, const float* __restrict__ stats,
        const float* __restrict__ gamma, const float* __restrict__ beta) {
    int bc = blockIdx.y;            // 512 = b*64 + c
    int c = bc & 63, b = bc >> 6;
    int g = c >> 3;
    float s = stats[(b * 8 + g) * 2], q = stats[(b * 8 + g) * 2 + 1];
    const float invN = 1.f / (8.f * N_POS);
    float mean = s * invN;
    float var = q * invN - mean * mean;
    float sc = rsqrtf(var + EPS);
    float ga = gamma[c] * sc;
    float be = beta[c] - mean * sc * gamma[c];
    size_t base = ((size_t)b * CDIM + c) * N_POS + (size_t)(blockIdx.x * 256 + threadIdx.x) * 4;
    uint2 u = *reinterpret_cast<const uint2*>(ybf + base);
    float4 v;
    v.x = bf2f((short)(u.x & 0xffff)); v.y = bf2f((short)(u.x >> 16));
    v.z = bf2f((short)(u.y & 0xffff)); v.w = bf2f((short)(u.y >> 16));
    v.x = v.x * ga + be; v.y = v.y * ga + be; v.z = v.z * ga + be; v.w = v.w * ga + be;
    *reinterpret_cast<float4*>(out + base) = v;
}

extern "C" void kernel_launch(void* const* d_in, const int* in_sizes, int n_in,
                              void* d_out, int out_size, void* d_ws, size_t ws_size,
                              hipStream_t stream) {
    const float* x     = (const float*)d_in[0];
    const float* Wqkv  = (const float*)d_in[1];
    const float* Wout  = (const float*)d_in[2];
    const float* bout  = (const float*)d_in[3];
    const float* gamma = (const float*)d_in[4];
    const float* beta  = (const float*)d_in[5];
    float* out = (float*)d_out;

    float* stats  = (float*)d_ws;
    float* Pparts = stats + 128;
    __hip_bfloat16* Ubf = (__hip_bfloat16*)(Pparts + NPART * PPART_SZ);
    __hip_bfloat16* wbf = (__hip_bfloat16*)((char*)Ubf + UBF_BYTES);
    __hip_bfloat16* ybf = (__hip_bfloat16*)((char*)wbf + WBF_BYTES);

    wprep_kernel<<<dim3(24), 256, 0, stream>>>(Wqkv, wbf, stats);
    qkp_kernel<<<dim3(72, BATCH), 256, 0, stream>>>(x, wbf, Pparts);
    umat_kernel<<<dim3(NCHUNK, BATCH, HEADS), 256, 0, stream>>>(Wout, Pparts, Ubf);
    vy_kernel<<<dim3(72, BATCH), 256, 0, stream>>>(x, wbf, Ubf, bout, ybf, stats);
    gn_kernel<<<dim3(9, 512), 256, 0, stream>>>(ybf, out, stats, gamma, beta);
}